// Round 15
// baseline (177.012 us; speedup 1.0000x reference)
//
#include <hip/hip_runtime.h>
#include <hip/hip_bf16.h>

// B=32, C=32, H=W=256, regions 4x4 of 64x64.
// Round 15: r14 (nt out-stores, pipelined staging) +
//  (a) finalize hoisted back to a 1-block kernel (wsA/wsB), removing the
//      per-conv-block 64-load loop + 2 barriers;
//  (b) conv tile = 4 rows, LDS [6][64][32] = 24KB -> 6 blocks/CU. The 1.5x
//      row-halo re-reads are L3 hits now (nt stores keep x resident).

#define EPS 1e-5f

typedef float f32x4 __attribute__((ext_vector_type(4)));
typedef __bf16 bf16x8 __attribute__((ext_vector_type(8)));
typedef short short8 __attribute__((ext_vector_type(8)));

__device__ inline short f2bf(float f) {
  union { __hip_bfloat16 h; short s; } u;
  u.h = __float2bfloat16(f);
  return u.s;
}

// ---------------- Kernel 1: per-(b,c) plane stats, contiguous sweep ----------
__global__ __launch_bounds__(256) void stats_partial(
    const float* __restrict__ x, float* __restrict__ ws_sum,
    float* __restrict__ ws_sq) {
  int plane = blockIdx.x;            // b*32 + c
  const float* base = x + (size_t)plane * 65536;
  int t = threadIdx.x;
  float s[4] = {0.f, 0.f, 0.f, 0.f}, q[4] = {0.f, 0.f, 0.f, 0.f};
#pragma unroll
  for (int R = 0; R < 4; ++R) {
#pragma unroll
    for (int ii = 0; ii < 16; ++ii) {
      int idx4 = (R * 16 + ii) * 256 + t;     // float4 index
      float4 v = *reinterpret_cast<const float4*>(base + (size_t)idx4 * 4);
      s[R] += (v.x + v.y) + (v.z + v.w);
      q[R] += (v.x * v.x + v.y * v.y) + (v.z * v.z + v.w * v.w);
    }
  }
#pragma unroll
  for (int R = 0; R < 4; ++R) {
#pragma unroll
    for (int off = 8; off; off >>= 1) {
      s[R] += __shfl_down(s[R], off);
      q[R] += __shfl_down(q[R], off);
    }
  }
  __shared__ float red[2][4][4][4];  // [s|q][wave][Cc][R]
  int lane = t & 63, wv = t >> 6;
  if ((lane & 15) == 0) {
    int Cc = lane >> 4;
#pragma unroll
    for (int R = 0; R < 4; ++R) {
      red[0][wv][Cc][R] = s[R];
      red[1][wv][Cc][R] = q[R];
    }
  }
  __syncthreads();
  if (t < 16) {                      // t == p
    int R = t >> 2, Cc = t & 3;
    float S = 0.f, Q = 0.f;
#pragma unroll
    for (int w = 0; w < 4; ++w) {
      S += red[0][w][Cc][R];
      Q += red[1][w][Cc][R];
    }
    ws_sum[plane * 16 + t] = S;
    ws_sq[plane * 16 + t] = Q;
  }
}

// ---------------- Kernel 2: finalize per-(p,c) scale/shift ----------------
__global__ __launch_bounds__(512) void stats_finalize(
    const float* __restrict__ ws_sum, const float* __restrict__ ws_sq,
    const float* __restrict__ gamma, const float* __restrict__ beta,
    float* __restrict__ wsA, float* __restrict__ wsB) {
  int j = threadIdx.x;               // 0..511
  int p = j >> 5, c = j & 31;
  float S = 0.f, Q = 0.f;
#pragma unroll
  for (int b = 0; b < 32; ++b) {
    int idx = (b * 32 + c) * 16 + p;
    S += ws_sum[idx];
    Q += ws_sq[idx];
  }
  const float inv = 1.0f / 131072.0f;
  float mean = S * inv;
  float var = Q * inv - mean * mean;
  float rstd = rsqrtf(var + EPS);
  float a = rstd * gamma[c];
  wsA[p * 32 + c] = a;
  wsB[p * 32 + c] = beta[c] - mean * a;
}

// ---------------- Kernel 3: pack conv_w into MFMA A-fragments ----------------
__global__ __launch_bounds__(256) void weights_prep(
    const float* __restrict__ conv_w, unsigned short* __restrict__ wfrag) {
  int idx = blockIdx.x * 256 + threadIdx.x;
  if (idx >= 18 * 64) return;
  int lane = idx & 63;
  int th = idx >> 6;                 // t*2 + h
  int t = th >> 1, h = th & 1;
  int dy = t / 3, dx = t - dy * 3;
  int oc = h * 16 + (lane & 15);
  int ic0 = (lane >> 4) * 8;
#pragma unroll
  for (int j = 0; j < 8; ++j) {
    float w = conv_w[((oc * 32 + ic0 + j) * 3 + dy) * 3 + dx];
    wfrag[(size_t)idx * 8 + j] = (unsigned short)f2bf(w);
  }
}

// ---------------- Kernel 4: normalize+prelu -> LDS bf16 -> MFMA conv --------
// block = (b, p, rt): 4 output rows x 64 cols. 4 waves. LDS [6][64][32] bf16
// = 24576 B -> 6 blocks/CU. slot swizzle (s + (col>>1)) & 3. nt out-stores.
__global__ __launch_bounds__(256) void conv_mfma(
    const float* __restrict__ x, const unsigned short* __restrict__ wfrag,
    const float* __restrict__ conv_b, const float* __restrict__ prelu_a,
    const float* __restrict__ wsA, const float* __restrict__ wsB,
    float* __restrict__ out) {
  __shared__ short lds_y[6 * 64 * 32];   // 24576 B

  int blk0 = blockIdx.x;             // 8192 blocks; chunked XCD swizzle
  int blk = (blk0 & 7) * 1024 + (blk0 >> 3);
  int rt = blk & 15;
  int p = (blk >> 4) & 15;
  int b = blk >> 8;
  int R = p >> 2, Cc = p & 3;
  int h0 = rt * 4;
  int tid = threadIdx.x;
  int lane = tid & 63;
  float pa = prelu_a[0];

  // per-thread-fixed staging decomposition
  int s = (tid >> 4) & 3;            // ic-slice
  int c4 = tid & 15;                 // col-quad
  int srb = tid >> 6;                // base staged-row 0..3
  int ic0 = s * 8;

  // norm coeffs for this thread's 8 channels (two float4 loads)
  float4 a0 = *reinterpret_cast<const float4*>(wsA + p * 32 + ic0);
  float4 a1 = *reinterpret_cast<const float4*>(wsA + p * 32 + ic0 + 4);
  float4 bb0 = *reinterpret_cast<const float4*>(wsB + p * 32 + ic0);
  float4 bb1 = *reinterpret_cast<const float4*>(wsB + p * 32 + ic0 + 4);
  float a_r[8] = {a0.x, a0.y, a0.z, a0.w, a1.x, a1.y, a1.z, a1.w};
  float b_r[8] = {bb0.x, bb0.y, bb0.z, bb0.w, bb1.x, bb1.y, bb1.z, bb1.w};

  // ---- staging helpers
  auto stage_load = [&](f32x4(&vv)[8], int sr) {
    int lr = h0 - 1 + sr;
#pragma unroll
    for (int kk = 0; kk < 8; ++kk) vv[kk] = f32x4{0.f, 0.f, 0.f, 0.f};
    if ((unsigned)lr < 64u) {
      const float* xp =
          x + (((size_t)(b * 32 + ic0) * 256 + R * 64 + lr) * 256) + Cc * 64 +
          c4 * 4;
#pragma unroll
      for (int kk = 0; kk < 8; ++kk)
        vv[kk] = *reinterpret_cast<const f32x4*>(xp + (size_t)kk * 65536);
    }
  };
  auto stage_write = [&](const f32x4(&vv)[8], int sr) {
#pragma unroll
    for (int j = 0; j < 4; ++j) {
      short8 pk;
#pragma unroll
      for (int kk = 0; kk < 8; ++kk) {
        float e = fmaf(a_r[kk], vv[kk][j], b_r[kk]);
        e = e > 0.f ? e : pa * e;
        pk[kk] = f2bf(e);
      }
      int col = c4 * 4 + j;
      int slot = (s + (col >> 1)) & 3;
      *reinterpret_cast<short8*>(&lds_y[(sr * 64 + col) * 32 + slot * 8]) = pk;
    }
  };

  // ---- 2-deep pipelined staging: rows srb (all), 4+srb (tid<128)
  {
    f32x4 va[8], vb[8];
    stage_load(va, srb);             // 8 loads in flight
    if (tid < 128) stage_load(vb, 4 + srb);   // +8 more in flight
    stage_write(va, srb);
    if (tid < 128) stage_write(vb, 4 + srb);
  }
  __syncthreads();

  // ---- weight fragments + bias (post-barrier)
  bf16x8 wf[18];
#pragma unroll
  for (int th = 0; th < 18; ++th) {
    short8 sv =
        *reinterpret_cast<const short8*>(wfrag + ((size_t)th * 64 + lane) * 8);
    wf[th] = __builtin_bit_cast(bf16x8, sv);
  }
  int l15 = lane & 15, l4 = lane >> 4;
  f32x4 bias0, bias1;
#pragma unroll
  for (int i = 0; i < 4; ++i) {
    bias0[i] = conv_b[l4 * 4 + i];
    bias1[i] = conv_b[16 + l4 * 4 + i];
  }

  // ---- MFMA: each wave does 4 groups (row wv, 4 col-blocks)
  int wv = tid >> 6;
  const short8 z8 = {0, 0, 0, 0, 0, 0, 0, 0};
  for (int g = 0; g < 4; ++g) {
    int r = wv;                      // one output row per wave
    int c0 = g * 16;
    f32x4 acc0 = bias0, acc1 = bias1;
#pragma unroll
    for (int t9 = 0; t9 < 9; ++t9) {
      const int dy = t9 / 3, dx = t9 - dy * 3;
      int sr = r + dy;               // 0..5
      int col_in = c0 + l15 + dx - 1;
      int colc = col_in & 63;
      int slot = (l4 + (colc >> 1)) & 3;
      short8 sv = *reinterpret_cast<const short8*>(
          &lds_y[(sr * 64 + colc) * 32 + slot * 8]);
      if (dx == 0) {
        if (c0 == 0 && l15 == 0) sv = z8;     // col -1 -> zero pad
      }
      if (dx == 2) {
        if (c0 == 48 && l15 == 15) sv = z8;   // col 64 -> zero pad
      }
      bf16x8 bv = __builtin_bit_cast(bf16x8, sv);
      acc0 = __builtin_amdgcn_mfma_f32_16x16x32_bf16(wf[t9 * 2], bv, acc0, 0, 0, 0);
      acc1 = __builtin_amdgcn_mfma_f32_16x16x32_bf16(wf[t9 * 2 + 1], bv, acc1, 0, 0, 0);
    }
    int grow = R * 64 + h0 + r;
    int gcol = Cc * 64 + c0 + l15;
    float* ob = out + (size_t)b * 2097152 + (size_t)grow * 256 + gcol;
#pragma unroll
    for (int i = 0; i < 4; ++i) {
      __builtin_nontemporal_store(acc0[i], &ob[(size_t)(l4 * 4 + i) * 65536]);
      __builtin_nontemporal_store(acc1[i],
                                  &ob[(size_t)(16 + l4 * 4 + i) * 65536]);
    }
  }
}

extern "C" void kernel_launch(void* const* d_in, const int* in_sizes, int n_in,
                              void* d_out, int out_size, void* d_ws,
                              size_t ws_size, hipStream_t stream) {
  const float* x = (const float*)d_in[0];
  const float* gamma = (const float*)d_in[1];
  const float* beta = (const float*)d_in[2];
  const float* prelu_a = (const float*)d_in[3];
  const float* conv_w = (const float*)d_in[4];
  const float* conv_b = (const float*)d_in[5];
  float* out = (float*)d_out;

  float* ws = (float*)d_ws;
  float* ws_sum = ws;                          // 16384 floats
  float* ws_sq = ws + 16384;                   // 16384
  float* wsA = ws + 32768;                     // 512
  float* wsB = ws + 33280;                     // 512
  unsigned short* wfrag = (unsigned short*)(ws + 33792);   // 9216 shorts

  weights_prep<<<5, 256, 0, stream>>>(conv_w, wfrag);
  stats_partial<<<1024, 256, 0, stream>>>(x, ws_sum, ws_sq);
  stats_finalize<<<1, 512, 0, stream>>>(ws_sum, ws_sq, gamma, beta, wsA, wsB);
  conv_mfma<<<8192, 256, 0, stream>>>(x, wfrag, conv_b, prelu_a, wsA, wsB,
                                      out);
}